// Round 1
// baseline (75.607 us; speedup 1.0000x reference)
//
#include <hip/hip_runtime.h>

#if __has_builtin(__builtin_amdgcn_exp2f)
__device__ __forceinline__ float fast_exp2(float x) { return __builtin_amdgcn_exp2f(x); }
#else
__device__ __forceinline__ float fast_exp2(float x) { return exp2f(x); }
#endif

constexpr int C_ = 256;   // centers
constexpr int D_ = 2;     // spatial dim
constexpr int M_ = 5;     // ensemble size
constexpr float LOG2E = 1.4426950408889634f;

// out[m,n,d] = sum_c exp(-||x_n - c||^2) * sigma^2 * W[m,c,d]
// sigma^2 = 0.0625 folded into exponent: exp2(-d2*log2e - 4)
__global__ __launch_bounds__(256) void ensemble_rbf_kernel(
    const float* __restrict__ x,        // [N,2]
    const float* __restrict__ centers,  // [256,2]
    const float* __restrict__ weights,  // [5,256,2]
    float* __restrict__ out,            // [5,N,2]
    int N)
{
    __shared__ float2 s_ctr[C_];
    __shared__ float4 s_w[C_][3];   // 10 weights + 2 pad per center, layout [c][m*2+d]

    const int tid = threadIdx.x;

    // stage centers (256 x float2, one per thread)
    s_ctr[tid] = ((const float2*)centers)[tid];

    // stage weights transposed [m][c][d] -> [c][m*2+d], row padded to 12 floats (16B aligned)
    float* wf = (float*)s_w;
    for (int i = tid; i < M_ * C_ * D_; i += 256) {
        int m = i >> 9;        // i / (C_*D_)
        int r = i & 511;       // i % (C_*D_)
        int c = r >> 1;
        int d = r & 1;
        wf[c * 12 + m * 2 + d] = weights[i];
    }
    __syncthreads();

    const int n = blockIdx.x * 256 + tid;
    if (n >= N) return;

    const float2 xv = ((const float2*)x)[n];

    float accx[M_], accy[M_];
    #pragma unroll
    for (int m = 0; m < M_; m++) { accx[m] = 0.f; accy[m] = 0.f; }

    #pragma unroll 4
    for (int c = 0; c < C_; c++) {
        // wave-uniform LDS reads -> broadcast, conflict-free
        float2 ctr = s_ctr[c];
        float dx = xv.x - ctr.x;
        float dy = xv.y - ctr.y;
        float d2 = fmaf(dx, dx, dy * dy);
        float r = fast_exp2(fmaf(d2, -LOG2E, -4.0f));  // exp(-d2) * 0.0625

        float4 w0 = s_w[c][0];
        float4 w1 = s_w[c][1];
        float4 w2 = s_w[c][2];
        accx[0] = fmaf(r, w0.x, accx[0]);  accy[0] = fmaf(r, w0.y, accy[0]);
        accx[1] = fmaf(r, w0.z, accx[1]);  accy[1] = fmaf(r, w0.w, accy[1]);
        accx[2] = fmaf(r, w1.x, accx[2]);  accy[2] = fmaf(r, w1.y, accy[2]);
        accx[3] = fmaf(r, w1.z, accx[3]);  accy[3] = fmaf(r, w1.w, accy[3]);
        accx[4] = fmaf(r, w2.x, accx[4]);  accy[4] = fmaf(r, w2.y, accy[4]);
    }

    // out[m][n] as float2: coalesced 8B/lane stores
    float2* out2 = (float2*)out;
    #pragma unroll
    for (int m = 0; m < M_; m++) {
        out2[(size_t)m * N + n] = make_float2(accx[m], accy[m]);
    }
}

extern "C" void kernel_launch(void* const* d_in, const int* in_sizes, int n_in,
                              void* d_out, int out_size, void* d_ws, size_t ws_size,
                              hipStream_t stream) {
    const float* x       = (const float*)d_in[0];  // [N,2]
    const float* centers = (const float*)d_in[1];  // [256,2]
    const float* weights = (const float*)d_in[2];  // [5,256,2]
    float* out = (float*)d_out;                    // [5,N,2]

    int N = in_sizes[0] / 2;
    int grid = (N + 255) / 256;
    ensemble_rbf_kernel<<<grid, 256, 0, stream>>>(x, centers, weights, out, N);
}

// Round 2
// 70.582 us; speedup vs baseline: 1.0712x; 1.0712x over previous
//
#include <hip/hip_runtime.h>

#if __has_builtin(__builtin_amdgcn_exp2f)
__device__ __forceinline__ float fast_exp2(float x) { return __builtin_amdgcn_exp2f(x); }
#else
__device__ __forceinline__ float fast_exp2(float x) { return exp2f(x); }
#endif

constexpr int C_ = 256;   // centers
constexpr int M_ = 5;     // ensemble size
constexpr float LOG2E = 1.4426950408889634f;

// out[m,n,d] = sum_c exp(-||x_n - c||^2) * sigma^2 * W[m,c,d],  sigma^2 = 1/16
// exp(-d2)/16 = exp2(-d2*log2e - 4)
//
// Block = 256 threads = 64 n  x  4 c-chunks (one wave per chunk, so the
// c index is wave-uniform -> all LDS table reads are broadcasts).
// Partial sums combined through an LDS reduction at the end.
__global__ __launch_bounds__(256) void ensemble_rbf_kernel(
    const float* __restrict__ x,        // [N,2]
    const float* __restrict__ centers,  // [256,2]
    const float* __restrict__ weights,  // [5,256,2]
    float* __restrict__ out,            // [5,N,2]
    int N)
{
    // packed table: per center c, 12 floats {cx, cy, w0..w9}, 48B row (16B aligned)
    // reused after the main loop as the reduction scratch [4][64][12]
    __shared__ float s_tab[C_ * 12];

    const int tid   = threadIdx.x;
    const int nl    = tid & 63;     // local n (lane)
    const int chunk = tid >> 6;     // wave id = c-chunk

    // ---- stage packed table: thread t fills row t ----
    {
        float2 cv = ((const float2*)centers)[tid];
        float* row = &s_tab[tid * 12];
        row[0] = cv.x;
        row[1] = cv.y;
        const float2* w2 = (const float2*)weights;   // [5][256] float2
        #pragma unroll
        for (int m = 0; m < M_; m++) {
            float2 wv = w2[m * C_ + tid];            // coalesced
            row[2 + 2 * m]     = wv.x;
            row[2 + 2 * m + 1] = wv.y;
        }
    }
    __syncthreads();

    const int n = blockIdx.x * 64 + nl;
    float2 xv = (n < N) ? ((const float2*)x)[n] : make_float2(0.f, 0.f);

    float accx[M_], accy[M_];
    #pragma unroll
    for (int m = 0; m < M_; m++) { accx[m] = 0.f; accy[m] = 0.f; }

    const float4* tab4 = (const float4*)s_tab;
    const int cbase = chunk * 64;

    #pragma unroll 8
    for (int cc = 0; cc < 64; cc++) {
        int c = cbase + cc;                 // wave-uniform
        float4 t0 = tab4[c * 3 + 0];        // {cx, cy, w0, w1}
        float4 t1 = tab4[c * 3 + 1];        // {w2, w3, w4, w5}
        float4 t2 = tab4[c * 3 + 2];        // {w6, w7, w8, w9}

        float dx = xv.x - t0.x;
        float dy = xv.y - t0.y;
        float d2 = fmaf(dx, dx, dy * dy);
        float r  = fast_exp2(fmaf(d2, -LOG2E, -4.0f));   // exp(-d2)/16

        accx[0] = fmaf(r, t0.z, accx[0]);  accy[0] = fmaf(r, t0.w, accy[0]);
        accx[1] = fmaf(r, t1.x, accx[1]);  accy[1] = fmaf(r, t1.y, accy[1]);
        accx[2] = fmaf(r, t1.z, accx[2]);  accy[2] = fmaf(r, t1.w, accy[2]);
        accx[3] = fmaf(r, t2.x, accx[3]);  accy[3] = fmaf(r, t2.y, accy[3]);
        accx[4] = fmaf(r, t2.z, accx[4]);  accy[4] = fmaf(r, t2.w, accy[4]);
    }

    // ---- combine the 4 chunk-partials per n via LDS ----
    __syncthreads();   // everyone done reading the table
    {
        float4* slot = (float4*)&s_tab[(chunk * 64 + nl) * 12];
        slot[0] = make_float4(accx[0], accy[0], accx[1], accy[1]);
        slot[1] = make_float4(accx[2], accy[2], accx[3], accy[3]);
        slot[2] = make_float4(accx[4], accy[4], 0.f, 0.f);
    }
    __syncthreads();

    if (tid < 64 && n < N) {
        float4 s0 = make_float4(0.f, 0.f, 0.f, 0.f);
        float4 s1 = s0, s2 = s0;
        #pragma unroll
        for (int k = 0; k < 4; k++) {
            const float4* slot = (const float4*)&s_tab[(k * 64 + nl) * 12];
            float4 r0 = slot[0], r1 = slot[1], r2 = slot[2];
            s0.x += r0.x; s0.y += r0.y; s0.z += r0.z; s0.w += r0.w;
            s1.x += r1.x; s1.y += r1.y; s1.z += r1.z; s1.w += r1.w;
            s2.x += r2.x; s2.y += r2.y;
        }
        float2* out2 = (float2*)out;
        out2[(size_t)0 * N + n] = make_float2(s0.x, s0.y);
        out2[(size_t)1 * N + n] = make_float2(s0.z, s0.w);
        out2[(size_t)2 * N + n] = make_float2(s1.x, s1.y);
        out2[(size_t)3 * N + n] = make_float2(s1.z, s1.w);
        out2[(size_t)4 * N + n] = make_float2(s2.x, s2.y);
    }
}

extern "C" void kernel_launch(void* const* d_in, const int* in_sizes, int n_in,
                              void* d_out, int out_size, void* d_ws, size_t ws_size,
                              hipStream_t stream) {
    const float* x       = (const float*)d_in[0];  // [N,2]
    const float* centers = (const float*)d_in[1];  // [256,2]
    const float* weights = (const float*)d_in[2];  // [5,256,2]
    float* out = (float*)d_out;                    // [5,N,2]

    int N = in_sizes[0] / 2;
    int grid = (N + 63) / 64;   // 64 n per block
    ensemble_rbf_kernel<<<grid, 256, 0, stream>>>(x, centers, weights, out, N);
}